// Round 8
// baseline (138.006 us; speedup 1.0000x reference)
//
#include <hip/hip_runtime.h>
#include <hip/hip_bf16.h>
#include <math.h>

#define L 1024
#define NB 2
#define DM 256
#define DI 512
#define DS 16
#define NC 64
#define CL 16

typedef unsigned int u32;
typedef unsigned short u16;
typedef short s16x8 __attribute__((ext_vector_type(8)));
typedef float f32x4 __attribute__((ext_vector_type(4)));

__device__ __forceinline__ float sigmoidf_(float x){ return 1.f/(1.f+__expf(-x)); }
__device__ __forceinline__ u16 f2bf(float v){
  u32 x = __float_as_uint(v);
  return (u16)((x + 0x7fffu + ((x >> 16) & 1u)) >> 16);
}
__device__ __forceinline__ float bf2f(u16 v){ return __uint_as_float((u32)v << 16); }

__device__ __forceinline__ void gload_lds16(const void* g, void* l){
  __builtin_amdgcn_global_load_lds((const __attribute__((address_space(1))) u32*)g,
                                   (__attribute__((address_space(3))) u32*)l, 16, 0, 0);
}

// ---------- combined: input transpose (blocks 0..127) + weight prep (rest)
#define SEG1 262144
#define SEG2 294912
#define SEG3 131072
#define SEGP (SEG1+SEG2+SEG3)
__global__ __launch_bounds__(256) void k_prep_trans(const float* __restrict__ x,
    float* __restrict__ u, u16* __restrict__ ub,
    const float* __restrict__ inw1, const float* __restrict__ xpw1, const float* __restrict__ dtw1, const float* __restrict__ outw1,
    const float* __restrict__ inw2, const float* __restrict__ xpw2, const float* __restrict__ dtw2, const float* __restrict__ outw2,
    u16* __restrict__ Wt1i, u16* __restrict__ Wt1x, u16* __restrict__ Wt1o,
    u16* __restrict__ Wt2i, u16* __restrict__ Wt2x, u16* __restrict__ Wt2o){
  __shared__ float T[64][65];
  if (blockIdx.x < 128){
    int t = threadIdx.x;
    int bidx = blockIdx.x;
    int lt = bidx & 15, ct = (bidx >> 4) & 3, b = bidx >> 6;
    int l0 = lt*64, c0 = ct*64;
    int lsub = (t & 15)*4, csub = t >> 4;
    #pragma unroll
    for (int i=0;i<4;++i){
      int c = csub + i*16;
      float4 v = *(const float4*)(x + ((size_t)(b*256 + c0 + c))*1024 + l0 + lsub);
      T[lsub+0][c]=v.x; T[lsub+1][c]=v.y; T[lsub+2][c]=v.z; T[lsub+3][c]=v.w;
    }
    __syncthreads();
    int cw = (t & 15)*4, lw = t >> 4;
    #pragma unroll
    for (int i=0;i<4;++i){
      int l = lw + i*16;
      float4 v = make_float4(T[l][cw], T[l][cw+1], T[l][cw+2], T[l][cw+3]);
      size_t o = ((size_t)(b*1024 + l0 + l))*256 + c0 + cw;
      *(float4*)(u + o) = v;
      *(ushort4*)(ub + o) = make_ushort4(f2bf(v.x), f2bf(v.y), f2bf(v.z), f2bf(v.w));
    }
    return;
  }
  int g = (blockIdx.x - 128)*256 + threadIdx.x;
  int p = g >= SEGP;
  int r = g - p*SEGP;
  const float* inw = p ? inw2 : inw1;  const float* xpw = p ? xpw2 : xpw1;
  const float* dtw = p ? dtw2 : dtw1;  const float* outw = p ? outw2 : outw1;
  u16* Wti = p ? Wt2i : Wt1i; u16* Wtx = p ? Wt2x : Wt1x;
  u16* Wto = p ? Wt2o : Wt1o;
  if (r < SEG1){
    int n = r >> 8, k = r & 255;
    Wti[r] = f2bf(inw[(size_t)k*1024 + n]);
  } else if (r < SEG1+SEG2){
    int q = r - SEG1; int n = q >> 9, k = q & 511;
    float v;
    if (n < 512){
      float acc = 0.f;
      #pragma unroll
      for (int j=0;j<16;++j) acc = fmaf(xpw[k*48 + j], dtw[j*512 + n], acc);
      v = acc;
    } else if (n < 544){
      v = xpw[k*48 + 16 + (n - 512)];
    } else v = 0.f;
    Wtx[q] = f2bf(v);
  } else {
    int q = r - SEG1 - SEG2; int n = q >> 9, k = q & 511;
    Wto[q] = f2bf(outw[(size_t)k*256 + n]);
  }
}

// ---------- in_proj GEMM (M=2048, N=1024, K=256):
// bn<8  (xs half):  write raw bf16 l-major -> xsb[2048][512]
// bn>=8 (res half): write silu(o) d-major  -> sresT[512][2048] (LDS transpose)
__global__ __launch_bounds__(256) void k_in_proj(const u16* __restrict__ A,
    const u16* __restrict__ Wt, const float* __restrict__ bias,
    u16* __restrict__ xsb, u16* __restrict__ sresT){
  __shared__ __align__(16) float smem[64*65];   // 16.6 KB; first 16 KB double as As/Bs
  u16* As = (u16*)smem;
  u16* Bs = As + 4096;
  int tid = threadIdx.x, lane = tid & 63, wid = tid >> 6;
  int bn = blockIdx.x, bm = blockIdx.y * 64;
  int bn64 = bn * 64;
  int wm = (wid >> 1) * 32, wn = (wid & 1) * 32;
  int lrow = lane & 15, lg = lane >> 4;
  int srow = tid >> 3, ssl = tid & 7;
  int sswz = ssl ^ (srow & 7);
  f32x4 acc[2][2] = {};
  for (int k0 = 0; k0 < 256; k0 += 64){
    #pragma unroll
    for (int i = 0; i < 2; ++i){
      int row = srow + i*32;
      gload_lds16(A  + (size_t)(bm + row)*256 + k0 + sswz*8, &As[row*64 + ssl*8]);
      gload_lds16(Wt + (size_t)(bn64 + row)*256 + k0 + sswz*8, &Bs[row*64 + ssl*8]);
    }
    __syncthreads();
    #pragma unroll
    for (int ks = 0; ks < 2; ++ks){
      int kg = ks*4 + lg;
      int swz = (kg ^ (lrow & 7)) << 3;
      s16x8 a[2], b[2];
      #pragma unroll
      for (int f = 0; f < 2; ++f){
        a[f] = *(const s16x8*)&As[(wm + f*16 + lrow)*64 + swz];
        b[f] = *(const s16x8*)&Bs[(wn + f*16 + lrow)*64 + swz];
      }
      #pragma unroll
      for (int i = 0; i < 2; ++i)
        #pragma unroll
        for (int j = 0; j < 2; ++j)
          acc[i][j] = __builtin_amdgcn_mfma_f32_16x16x32_bf16(a[i], b[j], acc[i][j], 0, 0, 0);
    }
    __syncthreads();
  }
  if (bn < 8){
    #pragma unroll
    for (int j=0;j<2;++j){
      int col_l = wn + j*16 + lrow;
      float bv = bias[bn64 + col_l];
      #pragma unroll
      for (int i=0;i<2;++i)
        #pragma unroll
        for (int r=0;r<4;++r){
          int row_l = wm + i*16 + lg*4 + r;
          xsb[(size_t)(bm + row_l)*512 + bn64 + col_l] = f2bf(acc[i][j][r] + bv);
        }
    }
  } else {
    float* CT = smem;
    #pragma unroll
    for (int j=0;j<2;++j){
      int col_l = wn + j*16 + lrow;
      float bv = bias[bn64 + col_l];
      #pragma unroll
      for (int i=0;i<2;++i)
        #pragma unroll
        for (int r=0;r<4;++r){
          int row_l = wm + i*16 + lg*4 + r;
          float o = acc[i][j][r] + bv;
          CT[row_l*65 + col_l] = o * sigmoidf_(o);
        }
    }
    __syncthreads();
    int d_local = tid >> 2, lseg = tid & 3;
    s16x8 r0, r1;
    #pragma unroll
    for (int i=0;i<8;++i){
      r0[i] = (short)f2bf(CT[(lseg*16+i)*65 + d_local]);
      r1[i] = (short)f2bf(CT[(lseg*16+8+i)*65 + d_local]);
    }
    u16* dst = sresT + (size_t)(bn64 - 512 + d_local)*2048 + bm + lseg*16;
    *(s16x8*)dst = r0; *(s16x8*)(dst+8) = r1;
  }
}

// ---------- conv+SiLU from xsb (bf16 l-major): xscT [512][2048] d-major + xscbl [2048][512] l-major
__global__ __launch_bounds__(256) void k_conv_t(const u16* __restrict__ xsb,
    const float* __restrict__ cw, const float* __restrict__ cb,
    u16* __restrict__ xscT, u16* __restrict__ xscbl){
  __shared__ float T[67*68];
  int tid = threadIdx.x;
  int d0 = (blockIdx.x & 7) * 64;
  int bm = (blockIdx.x >> 3) * 64;
  bool bstart = (bm & 1023) == 0;
  for (int base = tid; base < 67*8; base += 256){
    int r = base >> 3, q = base & 7;
    float v[8];
    if (r < 3 && bstart){
      #pragma unroll
      for (int k=0;k<8;++k) v[k] = 0.f;
    } else {
      s16x8 hv = *(const s16x8*)(xsb + (size_t)(bm - 3 + r)*512 + d0 + q*8);
      #pragma unroll
      for (int k=0;k<8;++k) v[k] = bf2f((u16)hv[k]);
    }
    #pragma unroll
    for (int k=0;k<8;++k) T[r*68 + q*8 + k] = v[k];
  }
  __syncthreads();
  int d_local = tid >> 2, lseg = tid & 3;
  int d = d0 + d_local;
  float4 wv = *(const float4*)(cw + d*4);
  float cbv = cb[d];
  float fo[16];
  float xm3 = T[(lseg*16+0)*68 + d_local];
  float xm2 = T[(lseg*16+1)*68 + d_local];
  float xm1 = T[(lseg*16+2)*68 + d_local];
  #pragma unroll
  for (int i=0;i<16;++i){
    float xc = T[(lseg*16+i+3)*68 + d_local];
    float o = cbv;
    o = fmaf(wv.x, xm3, o); o = fmaf(wv.y, xm2, o);
    o = fmaf(wv.z, xm1, o); o = fmaf(wv.w, xc, o);
    o *= sigmoidf_(o);
    fo[i] = o;
    xm3 = xm2; xm2 = xm1; xm1 = xc;
  }
  {
    s16x8 v0, v1;
    #pragma unroll
    for (int i=0;i<8;++i){ v0[i] = (short)f2bf(fo[i]); v1[i] = (short)f2bf(fo[8+i]); }
    u16* dst = xscT + (size_t)d*2048 + bm + lseg*16;
    *(s16x8*)dst = v0; *(s16x8*)(dst+8) = v1;
  }
  __syncthreads();
  #pragma unroll
  for (int i=0;i<16;++i) T[(lseg*16+i+3)*68 + d_local] = fo[i];
  __syncthreads();
  {
    int l_local = tid >> 2, dseg = tid & 3;
    s16x8 p0, p1;
    #pragma unroll
    for (int i=0;i<8;++i){
      p0[i] = (short)f2bf(T[(l_local+3)*68 + dseg*16 + i]);
      p1[i] = (short)f2bf(T[(l_local+3)*68 + dseg*16 + 8 + i]);
    }
    u16* dst2 = xscbl + (size_t)(bm + l_local)*512 + d0 + dseg*16;
    *(s16x8*)dst2 = p0; *(s16x8*)(dst2+8) = p1;
  }
}

// ---------- xproj GEMM (M=2048, N=576, K=512): cols<512 -> softplus -> dltT (d-major bf16),
// cols 512..543 -> BCb [2048][32] bf16.
__global__ __launch_bounds__(256) void k_xproj(const u16* __restrict__ A,
    const u16* __restrict__ Wt, const float* __restrict__ dtb,
    u16* __restrict__ dltT, u16* __restrict__ BCb){
  __shared__ __align__(16) float smem[64*69];
  u16* As = (u16*)smem;
  u16* Bs = As + 4096;
  int tid = threadIdx.x, lane = tid & 63, wid = tid >> 6;
  int bn = blockIdx.x, bm = blockIdx.y * 64;
  int bn64 = bn * 64;
  int wm = (wid >> 1) * 32, wn = (wid & 1) * 32;
  int lrow = lane & 15, lg = lane >> 4;
  int srow = tid >> 3, ssl = tid & 7;
  int sswz = ssl ^ (srow & 7);
  f32x4 acc[2][2] = {};
  for (int k0 = 0; k0 < 512; k0 += 64){
    #pragma unroll
    for (int i = 0; i < 2; ++i){
      int row = srow + i*32;
      gload_lds16(A  + (size_t)(bm + row)*512 + k0 + sswz*8, &As[row*64 + ssl*8]);
      gload_lds16(Wt + (size_t)(bn64 + row)*512 + k0 + sswz*8, &Bs[row*64 + ssl*8]);
    }
    __syncthreads();
    #pragma unroll
    for (int ks = 0; ks < 2; ++ks){
      int kg = ks*4 + lg;
      int swz = (kg ^ (lrow & 7)) << 3;
      s16x8 a[2], b[2];
      #pragma unroll
      for (int f = 0; f < 2; ++f){
        a[f] = *(const s16x8*)&As[(wm + f*16 + lrow)*64 + swz];
        b[f] = *(const s16x8*)&Bs[(wn + f*16 + lrow)*64 + swz];
      }
      #pragma unroll
      for (int i = 0; i < 2; ++i)
        #pragma unroll
        for (int j = 0; j < 2; ++j)
          acc[i][j] = __builtin_amdgcn_mfma_f32_16x16x32_bf16(a[i], b[j], acc[i][j], 0, 0, 0);
    }
    __syncthreads();
  }
  if (bn < 8){
    float* DT = smem;
    #pragma unroll
    for (int j=0;j<2;++j){
      int col_l = wn + j*16 + lrow;
      float bv = dtb[bn64 + col_l];
      #pragma unroll
      for (int i=0;i<2;++i)
        #pragma unroll
        for (int r=0;r<4;++r){
          int row_l = wm + i*16 + lg*4 + r;
          float a = acc[i][j][r] + bv;
          DT[row_l*69 + col_l] = fmaxf(a, 0.f) + log1pf(__expf(-fabsf(a)));
        }
    }
    __syncthreads();
    int c_local = tid >> 2, lseg = tid & 3;
    int dcol = bn64 + c_local;
    s16x8 v0, v1;
    #pragma unroll
    for (int i=0;i<8;++i){
      v0[i] = (short)f2bf(DT[(lseg*16+i)*69 + c_local]);
      v1[i] = (short)f2bf(DT[(lseg*16+8+i)*69 + c_local]);
    }
    u16* dst = dltT + (size_t)dcol*2048 + bm + lseg*16;
    *(s16x8*)dst = v0; *(s16x8*)(dst+8) = v1;
  } else {
    #pragma unroll
    for (int j=0;j<2;++j){
      int col_g = bn64 + wn + j*16 + lrow;
      if (col_g < 544){
        #pragma unroll
        for (int i=0;i<2;++i)
          #pragma unroll
          for (int r=0;r<4;++r){
            int row = bm + wm + i*16 + lg*4 + r;
            BCb[(size_t)row*32 + (col_g - 512)] = f2bf(acc[i][j][r]);
          }
      }
    }
  }
}

// ---------- fused scan: coalesced d-major bf16 inputs, LDS combine.
__global__ __launch_bounds__(256) void k_scan(const u16* __restrict__ dltT,
    const u16* __restrict__ xscT, const u16* __restrict__ BCb,
    const u16* __restrict__ sresT, const float* __restrict__ A_log,
    const float* __restrict__ Dp, u16* __restrict__ ygb){
  __shared__ float hbuf[64][68];
  __shared__ float SsumL[64][4];
  int tid = threadIdx.x;
  int chunk = tid >> 2, dl = tid & 3;
  int b = blockIdx.x >> 7, d0 = (blockIdx.x & 127) << 2;
  int d = d0 + dl;
  float A[DS];
  #pragma unroll
  for (int n=0;n<DS;++n) A[n] = -__expf(A_log[d*DS + n]);
  size_t cbase = (size_t)d*2048 + b*1024 + chunk*16;
  s16x8 dv0 = *(const s16x8*)(dltT + cbase);
  s16x8 dv1 = *(const s16x8*)(dltT + cbase + 8);
  s16x8 xv0 = *(const s16x8*)(xscT + cbase);
  s16x8 xv1 = *(const s16x8*)(xscT + cbase + 8);
  float dr[16], xq[16];
  #pragma unroll
  for (int i=0;i<8;++i){
    dr[i] = bf2f((u16)dv0[i]); dr[8+i] = bf2f((u16)dv1[i]);
    xq[i] = bf2f((u16)xv0[i]); xq[8+i] = bf2f((u16)xv1[i]);
  }
  float h[DS];
  #pragma unroll
  for (int n=0;n<DS;++n) h[n] = 0.f;
  float S = 0.f;
  int rbase = b*1024 + chunk*16;
  #pragma unroll
  for (int t=0;t<16;++t){
    const u16* bp = BCb + (size_t)(rbase + t)*32;
    s16x8 b0 = *(const s16x8*)bp;
    s16x8 b1 = *(const s16x8*)(bp + 8);
    float dlt = dr[t]; S += dlt;
    float dx = dlt * xq[t];
    #pragma unroll
    for (int n=0;n<8;++n) h[n] = fmaf(__expf(dlt*A[n]), h[n], dx*bf2f((u16)b0[n]));
    #pragma unroll
    for (int n=0;n<8;++n) h[8+n] = fmaf(__expf(dlt*A[8+n]), h[8+n], dx*bf2f((u16)b1[n]));
  }
  #pragma unroll
  for (int n=0;n<DS;++n) hbuf[chunk][dl*16+n] = h[n];
  SsumL[chunk][dl] = S;
  __syncthreads();
  if (tid < 64){
    int dl2 = tid & 3, n2 = tid >> 2;
    float An = -__expf(A_log[(d0+dl2)*DS + n2]);
    float hh = 0.f;
    for (int c=0;c<NC;++c){
      float he  = hbuf[c][dl2*16+n2];
      float dec = __expf(An * SsumL[c][dl2]);
      float nh  = fmaf(dec, hh, he);
      hbuf[c][dl2*16+n2] = hh;
      hh = nh;
    }
  }
  __syncthreads();
  #pragma unroll
  for (int n=0;n<DS;++n) h[n] = hbuf[chunk][dl*16+n];
  s16x8 s0 = *(const s16x8*)(sresT + cbase);
  s16x8 s1 = *(const s16x8*)(sresT + cbase + 8);
  float sr[16];
  #pragma unroll
  for (int i=0;i<8;++i){ sr[i] = bf2f((u16)s0[i]); sr[8+i] = bf2f((u16)s1[i]); }
  float Dv = Dp[d];
  #pragma unroll
  for (int t=0;t<16;++t){
    const u16* bp = BCb + (size_t)(rbase + t)*32;
    s16x8 b0 = *(const s16x8*)bp;
    s16x8 b1 = *(const s16x8*)(bp + 8);
    s16x8 c0 = *(const s16x8*)(bp + 16);
    s16x8 c1 = *(const s16x8*)(bp + 24);
    float dlt = dr[t];
    float dx = dlt * xq[t];
    float y = 0.f;
    #pragma unroll
    for (int n=0;n<8;++n){
      h[n] = fmaf(__expf(dlt*A[n]), h[n], dx*bf2f((u16)b0[n]));
      y = fmaf(h[n], bf2f((u16)c0[n]), y);
    }
    #pragma unroll
    for (int n=0;n<8;++n){
      h[8+n] = fmaf(__expf(dlt*A[8+n]), h[8+n], dx*bf2f((u16)b1[n]));
      y = fmaf(h[8+n], bf2f((u16)c1[n]), y);
    }
    y = fmaf(xq[t], Dv, y);
    ygb[(size_t)(rbase + t)*512 + d] = f2bf(y * sr[t]);
  }
}

// ---------- out-proj GEMM (M=2048, N=256, K=512) + bias + LayerNorm + residual + flip
// MODE 0: write u2[row][255-col] f32+bf16.  MODE 1: write d_out[b][255-col][l].
template<int MODE>
__global__ __launch_bounds__(256) void k_gemm_out_ln(const u16* __restrict__ A,
    const u16* __restrict__ Wt, const float* __restrict__ ob,
    const float* __restrict__ resid, const float* __restrict__ lnw, const float* __restrict__ lnb,
    float* __restrict__ out, u16* __restrict__ outb){
  __shared__ __align__(16) u16 As[64*64];
  __shared__ __align__(16) u16 Bs[256*64];
  __shared__ float redS[2][64], redQ[2][64];
  int tid = threadIdx.x, lane = tid & 63, wid = tid >> 6;
  int bm = blockIdx.x * 64;
  int wm = (wid & 1)*32, wn = (wid >> 1)*128;
  int lrow = lane & 15, lg = lane >> 4;
  int srow = tid >> 3, ssl = tid & 7;
  int sswz = ssl ^ (srow & 7);
  f32x4 acc[2][8] = {};
  for (int k0=0;k0<512;k0+=64){
    #pragma unroll
    for (int i=0;i<2;++i){
      int row = srow + i*32;
      gload_lds16(A + (size_t)(bm+row)*512 + k0 + sswz*8, &As[row*64 + ssl*8]);
    }
    #pragma unroll
    for (int i=0;i<8;++i){
      int row = srow + i*32;
      gload_lds16(Wt + (size_t)row*512 + k0 + sswz*8, &Bs[row*64 + ssl*8]);
    }
    __syncthreads();
    #pragma unroll
    for (int ks=0;ks<2;++ks){
      int kg = ks*4 + lg;
      int swz = (kg ^ (lrow & 7)) << 3;
      s16x8 a[2], bq[8];
      #pragma unroll
      for (int f=0;f<2;++f) a[f] = *(const s16x8*)&As[(wm + f*16 + lrow)*64 + swz];
      #pragma unroll
      for (int j=0;j<8;++j) bq[j] = *(const s16x8*)&Bs[(wn + j*16 + lrow)*64 + swz];
      #pragma unroll
      for (int f=0;f<2;++f)
        #pragma unroll
        for (int j=0;j<8;++j)
          acc[f][j] = __builtin_amdgcn_mfma_f32_16x16x32_bf16(a[f], bq[j], acc[f][j], 0, 0, 0);
    }
    __syncthreads();
  }
  float bv[8], lw[8], lb[8];
  #pragma unroll
  for (int j=0;j<8;++j){
    int col = wn + j*16 + lrow;
    bv[j] = ob[col]; lw[j] = lnw[col]; lb[j] = lnb[col];
  }
  #pragma unroll
  for (int i=0;i<2;++i)
    #pragma unroll
    for (int r=0;r<4;++r){
      float s=0.f, q=0.f;
      #pragma unroll
      for (int j=0;j<8;++j){ float v = acc[i][j][r] + bv[j]; s += v; q = fmaf(v, v, q); }
      #pragma unroll
      for (int m=1;m<=8;m<<=1){ s += __shfl_xor(s, m, 64); q += __shfl_xor(q, m, 64); }
      if (lrow == 0){ int row = wm + i*16 + lg*4 + r; redS[wn>>7][row] = s; redQ[wn>>7][row] = q; }
    }
  __syncthreads();
  #pragma unroll
  for (int i=0;i<2;++i)
    #pragma unroll
    for (int r=0;r<4;++r){
      int row = wm + i*16 + lg*4 + r;
      int grow = bm + row;
      float S = redS[0][row] + redS[1][row];
      float Q = redQ[0][row] + redQ[1][row];
      float mu = S * (1.f/256.f);
      float var = Q * (1.f/256.f) - mu*mu;
      float inv = rsqrtf(var + 1e-5f);
      #pragma unroll
      for (int j=0;j<8;++j){
        int col = wn + j*16 + lrow;
        float v = acc[i][j][r] + bv[j];
        float o = resid[(size_t)grow*256 + col] + (v - mu)*inv*lw[j] + lb[j];
        if (MODE == 0){
          out[(size_t)grow*256 + 255 - col]  = o;
          outb[(size_t)grow*256 + 255 - col] = f2bf(o);
        } else {
          int bb = grow >> 10, ll = grow & 1023;
          out[(((size_t)bb*256) + (255 - col))*1024 + ll] = o;
        }
      }
    }
}

extern "C" void kernel_launch(void* const* d_in, const int* in_sizes, int n_in,
                              void* d_out, int out_size, void* d_ws, size_t ws_size,
                              hipStream_t stream) {
  const float* x    = (const float*)d_in[0];
  const float* ln1w = (const float*)d_in[1];
  const float* ln1b = (const float*)d_in[2];
  const float* ln2w = (const float*)d_in[3];
  const float* ln2b = (const float*)d_in[4];

  const float* m1[11]; const float* m2[11];
  for (int i=0;i<11;++i){ m1[i] = (const float*)d_in[5+i]; m2[i] = (const float*)d_in[16+i]; }
  // order: in_w, in_b, conv_w, conv_b, xproj_w, dt_w, dt_b, A_log, D, out_w, out_b

  float* ws = (float*)d_ws;
  float* u0    = ws;                         // 524288
  u16*   u0b   = (u16*)(ws + 524288);        // 131072 fl
  u16*   xsb   = (u16*)(ws + 655360);        // 524288 fl : [2048][512] raw xs bf16
  u16*   xscbl = (u16*)(ws + 1179648);       // 524288 fl : [2048][512]
  u16*   xscT  = (u16*)(ws + 1703936);       // 524288 fl : [512][2048]
  u16*   sresT = (u16*)(ws + 2228224);       // 524288 fl : [512][2048]
  u16*   dltT  = (u16*)(ws + 2752512);       // 524288 fl : [512][2048]
  u16*   BCb   = (u16*)(ws + 3276800);       // 32768 fl  : [2048][32]
  u16*   ygb   = (u16*)(ws + 3309568);       // 524288 fl : [2048][512]
  float* u2    = ws + 3833856;               // 524288
  u16*   u2b   = (u16*)(ws + 4358144);       // 131072 fl
  u16*   Wt1i  = (u16*)(ws + 4489216);       // 131072 fl
  u16*   Wt1x  = (u16*)(ws + 4620288);       // 147456 fl
  u16*   Wt1o  = (u16*)(ws + 4767744);       // 65536 fl
  u16*   Wt2i  = (u16*)(ws + 4833280);       // 131072 fl
  u16*   Wt2x  = (u16*)(ws + 4964352);       // 147456 fl
  u16*   Wt2o  = (u16*)(ws + 5111808);       // 65536 fl
  // total 5177344 floats = 20.7 MB

  dim3 b256(256);
  k_prep_trans<<<128 + 2*SEGP/256, b256, 0, stream>>>(x, u0, u0b,
      m1[0], m1[4], m1[5], m1[9], m2[0], m2[4], m2[5], m2[9],
      Wt1i, Wt1x, Wt1o, Wt2i, Wt2x, Wt2o);

  // ---- block 1
  k_in_proj<<<dim3(16,32), b256, 0, stream>>>(u0b, Wt1i, m1[1], xsb, sresT);
  k_conv_t<<<256, b256, 0, stream>>>(xsb, m1[2], m1[3], xscT, xscbl);
  k_xproj<<<dim3(9,32), b256, 0, stream>>>(xscbl, Wt1x, m1[6], dltT, BCb);
  k_scan<<<256, b256, 0, stream>>>(dltT, xscT, BCb, sresT, m1[7], m1[8], ygb);
  k_gemm_out_ln<0><<<32, b256, 0, stream>>>(ygb, Wt1o, m1[10], u0, ln1w, ln1b, u2, u2b);

  // ---- block 2
  k_in_proj<<<dim3(16,32), b256, 0, stream>>>(u2b, Wt2i, m2[1], xsb, sresT);
  k_conv_t<<<256, b256, 0, stream>>>(xsb, m2[2], m2[3], xscT, xscbl);
  k_xproj<<<dim3(9,32), b256, 0, stream>>>(xscbl, Wt2x, m2[6], dltT, BCb);
  k_scan<<<256, b256, 0, stream>>>(dltT, xscT, BCb, sresT, m2[7], m2[8], ygb);
  k_gemm_out_ln<1><<<32, b256, 0, stream>>>(ygb, Wt2o, m2[10], u2, ln2w, ln2b, (float*)d_out, nullptr);
}

// Round 9
// 125.021 us; speedup vs baseline: 1.1039x; 1.1039x over previous
//
#include <hip/hip_runtime.h>
#include <hip/hip_bf16.h>
#include <math.h>

#define L 1024
#define NB 2
#define DM 256
#define DI 512
#define DS 16
#define NC 64
#define CL 16

typedef unsigned int u32;
typedef unsigned short u16;
typedef short s16x8 __attribute__((ext_vector_type(8)));
typedef float f32x4 __attribute__((ext_vector_type(4)));

__device__ __forceinline__ float sigmoidf_(float x){ return 1.f/(1.f+__expf(-x)); }
__device__ __forceinline__ u16 f2bf(float v){
  u32 x = __float_as_uint(v);
  return (u16)((x + 0x7fffu + ((x >> 16) & 1u)) >> 16);
}
__device__ __forceinline__ float bf2f(u16 v){ return __uint_as_float((u32)v << 16); }

__device__ __forceinline__ void gload_lds16(const void* g, void* l){
  __builtin_amdgcn_global_load_lds((const __attribute__((address_space(1))) u32*)g,
                                   (__attribute__((address_space(3))) u32*)l, 16, 0, 0);
}

// ---------- combined: input transpose (blocks 0..127) + weight prep (rest)
#define SEG1 262144
#define SEG2 294912
#define SEG3 131072
#define SEGP (SEG1+SEG2+SEG3)
__global__ __launch_bounds__(256) void k_prep_trans(const float* __restrict__ x,
    float* __restrict__ u, u16* __restrict__ ub,
    const float* __restrict__ inw1, const float* __restrict__ xpw1, const float* __restrict__ dtw1, const float* __restrict__ outw1,
    const float* __restrict__ inw2, const float* __restrict__ xpw2, const float* __restrict__ dtw2, const float* __restrict__ outw2,
    u16* __restrict__ Wt1i, u16* __restrict__ Wt1x, u16* __restrict__ Wt1o,
    u16* __restrict__ Wt2i, u16* __restrict__ Wt2x, u16* __restrict__ Wt2o){
  __shared__ float T[64][65];
  if (blockIdx.x < 128){
    int t = threadIdx.x;
    int bidx = blockIdx.x;
    int lt = bidx & 15, ct = (bidx >> 4) & 3, b = bidx >> 6;
    int l0 = lt*64, c0 = ct*64;
    int lsub = (t & 15)*4, csub = t >> 4;
    #pragma unroll
    for (int i=0;i<4;++i){
      int c = csub + i*16;
      float4 v = *(const float4*)(x + ((size_t)(b*256 + c0 + c))*1024 + l0 + lsub);
      T[lsub+0][c]=v.x; T[lsub+1][c]=v.y; T[lsub+2][c]=v.z; T[lsub+3][c]=v.w;
    }
    __syncthreads();
    int cw = (t & 15)*4, lw = t >> 4;
    #pragma unroll
    for (int i=0;i<4;++i){
      int l = lw + i*16;
      float4 v = make_float4(T[l][cw], T[l][cw+1], T[l][cw+2], T[l][cw+3]);
      size_t o = ((size_t)(b*1024 + l0 + l))*256 + c0 + cw;
      *(float4*)(u + o) = v;
      *(ushort4*)(ub + o) = make_ushort4(f2bf(v.x), f2bf(v.y), f2bf(v.z), f2bf(v.w));
    }
    return;
  }
  int g = (blockIdx.x - 128)*256 + threadIdx.x;
  int p = g >= SEGP;
  int r = g - p*SEGP;
  const float* inw = p ? inw2 : inw1;  const float* xpw = p ? xpw2 : xpw1;
  const float* dtw = p ? dtw2 : dtw1;  const float* outw = p ? outw2 : outw1;
  u16* Wti = p ? Wt2i : Wt1i; u16* Wtx = p ? Wt2x : Wt1x;
  u16* Wto = p ? Wt2o : Wt1o;
  if (r < SEG1){
    int n = r >> 8, k = r & 255;
    Wti[r] = f2bf(inw[(size_t)k*1024 + n]);
  } else if (r < SEG1+SEG2){
    int q = r - SEG1; int n = q >> 9, k = q & 511;
    float v;
    if (n < 512){
      float acc = 0.f;
      #pragma unroll
      for (int j=0;j<16;++j) acc = fmaf(xpw[k*48 + j], dtw[j*512 + n], acc);
      v = acc;
    } else if (n < 544){
      v = xpw[k*48 + 16 + (n - 512)];
    } else v = 0.f;
    Wtx[q] = f2bf(v);
  } else {
    int q = r - SEG1 - SEG2; int n = q >> 9, k = q & 511;
    Wto[q] = f2bf(outw[(size_t)k*256 + n]);
  }
}

// ---------- MFMA bf16 GEMM: C[M][N] f32 = A[M][K]bf16 @ Wt[N][K]bf16^T (+bias)
__global__ __launch_bounds__(256) void k_gemm_mfma(const u16* __restrict__ A,
    const u16* __restrict__ Wt, const float* __restrict__ bias,
    float* __restrict__ C, int M, int N, int K){
  __shared__ __align__(16) u16 As[64*64];
  __shared__ __align__(16) u16 Bs[64*64];
  int tid = threadIdx.x, lane = tid & 63, wid = tid >> 6;
  int bm = blockIdx.y * 64, bn = blockIdx.x * 64;
  int wm = (wid >> 1) * 32, wn = (wid & 1) * 32;
  int lrow = lane & 15, lg = lane >> 4;
  int srow = tid >> 3, ssl = tid & 7;
  int sswz = ssl ^ (srow & 7);
  f32x4 acc[2][2] = {};
  for (int k0 = 0; k0 < K; k0 += 64){
    #pragma unroll
    for (int i = 0; i < 2; ++i){
      int row = srow + i*32;
      gload_lds16(A  + (size_t)(bm + row)*K + k0 + sswz*8, &As[row*64 + ssl*8]);
      gload_lds16(Wt + (size_t)(bn + row)*K + k0 + sswz*8, &Bs[row*64 + ssl*8]);
    }
    __syncthreads();
    #pragma unroll
    for (int ks = 0; ks < 2; ++ks){
      int kg = ks*4 + lg;
      int swz = (kg ^ (lrow & 7)) << 3;
      s16x8 a[2], b[2];
      #pragma unroll
      for (int f = 0; f < 2; ++f){
        a[f] = *(const s16x8*)&As[(wm + f*16 + lrow)*64 + swz];
        b[f] = *(const s16x8*)&Bs[(wn + f*16 + lrow)*64 + swz];
      }
      #pragma unroll
      for (int i = 0; i < 2; ++i)
        #pragma unroll
        for (int j = 0; j < 2; ++j)
          acc[i][j] = __builtin_amdgcn_mfma_f32_16x16x32_bf16(a[i], b[j], acc[i][j], 0, 0, 0);
    }
    __syncthreads();
  }
  #pragma unroll
  for (int j = 0; j < 2; ++j){
    int col = bn + wn + j*16 + lrow;
    if (col < N){
      float bv = bias ? bias[col] : 0.f;
      #pragma unroll
      for (int i = 0; i < 2; ++i)
        #pragma unroll
        for (int r = 0; r < 4; ++r){
          int row = bm + wm + i*16 + lg*4 + r;
          C[(size_t)row*N + col] = acc[i][j][r] + bv;
        }
    }
  }
}

// ---------- conv+SiLU from xr (fp32), emitting scan-friendly layouts
__global__ __launch_bounds__(256) void k_conv_t(const float* __restrict__ xr,
    const float* __restrict__ cw, const float* __restrict__ cb,
    u16* __restrict__ xscT, u16* __restrict__ xscbl, u16* __restrict__ sresT){
  __shared__ float T[67*68];
  int tid = threadIdx.x;
  int d0 = (blockIdx.x & 7) * 64;
  int bm = (blockIdx.x >> 3) * 64;
  bool bstart = (bm & 1023) == 0;
  for (int base = tid; base < 67*16; base += 256){
    int r = base >> 4, q = base & 15;
    float4 v;
    if (r < 3 && bstart) v = make_float4(0.f,0.f,0.f,0.f);
    else v = *(const float4*)(xr + (size_t)(bm - 3 + r)*1024 + d0 + q*4);
    *(float4*)&T[r*68 + q*4] = v;
  }
  __syncthreads();
  int d_local = tid >> 2, lseg = tid & 3;
  int d = d0 + d_local;
  float4 wv = *(const float4*)(cw + d*4);
  float cbv = cb[d];
  float fo[16];
  float xm3 = T[(lseg*16+0)*68 + d_local];
  float xm2 = T[(lseg*16+1)*68 + d_local];
  float xm1 = T[(lseg*16+2)*68 + d_local];
  #pragma unroll
  for (int i=0;i<16;++i){
    float xc = T[(lseg*16+i+3)*68 + d_local];
    float o = cbv;
    o = fmaf(wv.x, xm3, o); o = fmaf(wv.y, xm2, o);
    o = fmaf(wv.z, xm1, o); o = fmaf(wv.w, xc, o);
    o *= sigmoidf_(o);
    fo[i] = o;
    xm3 = xm2; xm2 = xm1; xm1 = xc;
  }
  {
    s16x8 v0, v1;
    #pragma unroll
    for (int i=0;i<8;++i){ v0[i] = (short)f2bf(fo[i]); v1[i] = (short)f2bf(fo[8+i]); }
    u16* dst = xscT + (size_t)d*2048 + bm + lseg*16;
    *(s16x8*)dst = v0; *(s16x8*)(dst+8) = v1;
  }
  __syncthreads();
  #pragma unroll
  for (int i=0;i<16;++i) T[(lseg*16+i+3)*68 + d_local] = fo[i];
  __syncthreads();
  {
    int l_local = tid >> 2, dseg = tid & 3;
    s16x8 p0, p1;
    #pragma unroll
    for (int i=0;i<8;++i){
      p0[i] = (short)f2bf(T[(l_local+3)*68 + dseg*16 + i]);
      p1[i] = (short)f2bf(T[(l_local+3)*68 + dseg*16 + 8 + i]);
    }
    u16* dst2 = xscbl + (size_t)(bm + l_local)*512 + d0 + dseg*16;
    *(s16x8*)dst2 = p0; *(s16x8*)(dst2+8) = p1;
  }
  __syncthreads();
  for (int base = tid; base < 64*16; base += 256){
    int r = base >> 4, q = base & 15;
    float4 v = *(const float4*)(xr + (size_t)(bm + r)*1024 + 512 + d0 + q*4);
    v.x *= sigmoidf_(v.x); v.y *= sigmoidf_(v.y);
    v.z *= sigmoidf_(v.z); v.w *= sigmoidf_(v.w);
    *(float4*)&T[r*68 + q*4] = v;
  }
  __syncthreads();
  {
    s16x8 r0, r1;
    #pragma unroll
    for (int i=0;i<8;++i){
      r0[i] = (short)f2bf(T[(lseg*16+i)*68 + d_local]);
      r1[i] = (short)f2bf(T[(lseg*16+8+i)*68 + d_local]);
    }
    u16* dst3 = sresT + (size_t)d*2048 + bm + lseg*16;
    *(s16x8*)dst3 = r0; *(s16x8*)(dst3+8) = r1;
  }
}

// ---------- xproj GEMM (M=2048, N=576, K=512): cols<512 -> softplus -> dltT (d-major bf16),
// cols 512..543 -> BCb [2048][32] bf16.
__global__ __launch_bounds__(256) void k_xproj(const u16* __restrict__ A,
    const u16* __restrict__ Wt, const float* __restrict__ dtb,
    u16* __restrict__ dltT, u16* __restrict__ BCb){
  __shared__ __align__(16) float smem[64*69];
  u16* As = (u16*)smem;
  u16* Bs = As + 4096;
  int tid = threadIdx.x, lane = tid & 63, wid = tid >> 6;
  int bn = blockIdx.x, bm = blockIdx.y * 64;
  int bn64 = bn * 64;
  int wm = (wid >> 1) * 32, wn = (wid & 1) * 32;
  int lrow = lane & 15, lg = lane >> 4;
  int srow = tid >> 3, ssl = tid & 7;
  int sswz = ssl ^ (srow & 7);
  f32x4 acc[2][2] = {};
  for (int k0 = 0; k0 < 512; k0 += 64){
    #pragma unroll
    for (int i = 0; i < 2; ++i){
      int row = srow + i*32;
      gload_lds16(A  + (size_t)(bm + row)*512 + k0 + sswz*8, &As[row*64 + ssl*8]);
      gload_lds16(Wt + (size_t)(bn64 + row)*512 + k0 + sswz*8, &Bs[row*64 + ssl*8]);
    }
    __syncthreads();
    #pragma unroll
    for (int ks = 0; ks < 2; ++ks){
      int kg = ks*4 + lg;
      int swz = (kg ^ (lrow & 7)) << 3;
      s16x8 a[2], b[2];
      #pragma unroll
      for (int f = 0; f < 2; ++f){
        a[f] = *(const s16x8*)&As[(wm + f*16 + lrow)*64 + swz];
        b[f] = *(const s16x8*)&Bs[(wn + f*16 + lrow)*64 + swz];
      }
      #pragma unroll
      for (int i = 0; i < 2; ++i)
        #pragma unroll
        for (int j = 0; j < 2; ++j)
          acc[i][j] = __builtin_amdgcn_mfma_f32_16x16x32_bf16(a[i], b[j], acc[i][j], 0, 0, 0);
    }
    __syncthreads();
  }
  if (bn < 8){
    float* DT = smem;
    #pragma unroll
    for (int j=0;j<2;++j){
      int col_l = wn + j*16 + lrow;
      float bv = dtb[bn64 + col_l];
      #pragma unroll
      for (int i=0;i<2;++i)
        #pragma unroll
        for (int r=0;r<4;++r){
          int row_l = wm + i*16 + lg*4 + r;
          float a = acc[i][j][r] + bv;
          DT[row_l*69 + col_l] = fmaxf(a, 0.f) + log1pf(__expf(-fabsf(a)));
        }
    }
    __syncthreads();
    int c_local = tid >> 2, lseg = tid & 3;
    int dcol = bn64 + c_local;
    s16x8 v0, v1;
    #pragma unroll
    for (int i=0;i<8;++i){
      v0[i] = (short)f2bf(DT[(lseg*16+i)*69 + c_local]);
      v1[i] = (short)f2bf(DT[(lseg*16+8+i)*69 + c_local]);
    }
    u16* dst = dltT + (size_t)dcol*2048 + bm + lseg*16;
    *(s16x8*)dst = v0; *(s16x8*)(dst+8) = v1;
  } else {
    #pragma unroll
    for (int j=0;j<2;++j){
      int col_g = bn64 + wn + j*16 + lrow;
      if (col_g < 544){
        #pragma unroll
        for (int i=0;i<2;++i)
          #pragma unroll
          for (int r=0;r<4;++r){
            int row = bm + wm + i*16 + lg*4 + r;
            BCb[(size_t)row*32 + (col_g - 512)] = f2bf(acc[i][j][r]);
          }
      }
    }
  }
}

// ---------- fused scan: coalesced d-major bf16 inputs, LDS combine.
__global__ __launch_bounds__(256) void k_scan(const u16* __restrict__ dltT,
    const u16* __restrict__ xscT, const u16* __restrict__ BCb,
    const u16* __restrict__ sresT, const float* __restrict__ A_log,
    const float* __restrict__ Dp, u16* __restrict__ ygb){
  __shared__ float hbuf[64][68];
  __shared__ float SsumL[64][4];
  int tid = threadIdx.x;
  int chunk = tid >> 2, dl = tid & 3;
  int b = blockIdx.x >> 7, d0 = (blockIdx.x & 127) << 2;
  int d = d0 + dl;
  float A[DS];
  #pragma unroll
  for (int n=0;n<DS;++n) A[n] = -__expf(A_log[d*DS + n]);
  size_t cbase = (size_t)d*2048 + b*1024 + chunk*16;
  s16x8 dv0 = *(const s16x8*)(dltT + cbase);
  s16x8 dv1 = *(const s16x8*)(dltT + cbase + 8);
  s16x8 xv0 = *(const s16x8*)(xscT + cbase);
  s16x8 xv1 = *(const s16x8*)(xscT + cbase + 8);
  float dr[16], xq[16];
  #pragma unroll
  for (int i=0;i<8;++i){
    dr[i] = bf2f((u16)dv0[i]); dr[8+i] = bf2f((u16)dv1[i]);
    xq[i] = bf2f((u16)xv0[i]); xq[8+i] = bf2f((u16)xv1[i]);
  }
  float h[DS];
  #pragma unroll
  for (int n=0;n<DS;++n) h[n] = 0.f;
  float S = 0.f;
  int rbase = b*1024 + chunk*16;
  #pragma unroll
  for (int t=0;t<16;++t){
    const u16* bp = BCb + (size_t)(rbase + t)*32;
    s16x8 b0 = *(const s16x8*)bp;
    s16x8 b1 = *(const s16x8*)(bp + 8);
    float dlt = dr[t]; S += dlt;
    float dx = dlt * xq[t];
    #pragma unroll
    for (int n=0;n<8;++n) h[n] = fmaf(__expf(dlt*A[n]), h[n], dx*bf2f((u16)b0[n]));
    #pragma unroll
    for (int n=0;n<8;++n) h[8+n] = fmaf(__expf(dlt*A[8+n]), h[8+n], dx*bf2f((u16)b1[n]));
  }
  #pragma unroll
  for (int n=0;n<DS;++n) hbuf[chunk][dl*16+n] = h[n];
  SsumL[chunk][dl] = S;
  __syncthreads();
  if (tid < 64){
    int dl2 = tid & 3, n2 = tid >> 2;
    float An = -__expf(A_log[(d0+dl2)*DS + n2]);
    float hh = 0.f;
    for (int c=0;c<NC;++c){
      float he  = hbuf[c][dl2*16+n2];
      float dec = __expf(An * SsumL[c][dl2]);
      float nh  = fmaf(dec, hh, he);
      hbuf[c][dl2*16+n2] = hh;
      hh = nh;
    }
  }
  __syncthreads();
  #pragma unroll
  for (int n=0;n<DS;++n) h[n] = hbuf[chunk][dl*16+n];
  s16x8 s0 = *(const s16x8*)(sresT + cbase);
  s16x8 s1 = *(const s16x8*)(sresT + cbase + 8);
  float sr[16];
  #pragma unroll
  for (int i=0;i<8;++i){ sr[i] = bf2f((u16)s0[i]); sr[8+i] = bf2f((u16)s1[i]); }
  float Dv = Dp[d];
  #pragma unroll
  for (int t=0;t<16;++t){
    const u16* bp = BCb + (size_t)(rbase + t)*32;
    s16x8 b0 = *(const s16x8*)bp;
    s16x8 b1 = *(const s16x8*)(bp + 8);
    s16x8 c0 = *(const s16x8*)(bp + 16);
    s16x8 c1 = *(const s16x8*)(bp + 24);
    float dlt = dr[t];
    float dx = dlt * xq[t];
    float y = 0.f;
    #pragma unroll
    for (int n=0;n<8;++n){
      h[n] = fmaf(__expf(dlt*A[n]), h[n], dx*bf2f((u16)b0[n]));
      y = fmaf(h[n], bf2f((u16)c0[n]), y);
    }
    #pragma unroll
    for (int n=0;n<8;++n){
      h[8+n] = fmaf(__expf(dlt*A[8+n]), h[8+n], dx*bf2f((u16)b1[n]));
      y = fmaf(h[8+n], bf2f((u16)c1[n]), y);
    }
    y = fmaf(xq[t], Dv, y);
    ygb[(size_t)(rbase + t)*512 + d] = f2bf(y * sr[t]);
  }
}

// ---------- out-proj GEMM (BM=16, N=256, K=512) + bias + LN + residual + flip; 128 blocks.
// MODE 0: u2[row][255-col] f32+bf16.  MODE 1: d_out[b][255-col][l] (LDS-transposed, coalesced).
template<int MODE>
__global__ __launch_bounds__(256) void k_out_ln(const u16* __restrict__ A,
    const u16* __restrict__ Wt, const float* __restrict__ ob,
    const float* __restrict__ resid, const float* __restrict__ lnw, const float* __restrict__ lnb,
    float* __restrict__ out, u16* __restrict__ outb){
  __shared__ __align__(16) u16 As[16*512];   // full-K A tile (16 KB)
  __shared__ __align__(16) u16 Bs[256*64];   // per-kstep B tile (32 KB); reused as TT in MODE1
  __shared__ float redS[4][16], redQ[4][16];
  int tid = threadIdx.x, lane = tid & 63, wid = tid >> 6;
  int bm = blockIdx.x * 16;
  int wn = wid * 64;
  int lrow = lane & 15, lg = lane >> 4;
  // stage full A tile: 4 rounds x 256 lanes x 16B, swizzled global source, linear LDS dest
  #pragma unroll
  for (int rd = 0; rd < 4; ++rd){
    int e = rd*2048 + tid*8;           // u16 element index into As
    int r = e >> 9;                    // row 0..15
    int s = (e >> 3) & 63;             // 8-elem slot within row
    gload_lds16(A + (size_t)(bm + r)*512 + ((s ^ (r & 7)) << 3), &As[e]);
  }
  int srow = tid >> 3, ssl = tid & 7;
  f32x4 acc[4] = {};
  for (int k0 = 0; k0 < 512; k0 += 64){
    #pragma unroll
    for (int i = 0; i < 8; ++i){
      int row = srow + i*32;
      gload_lds16(Wt + (size_t)row*512 + k0 + ((ssl ^ (row & 7)) << 3), &Bs[row*64 + ssl*8]);
    }
    __syncthreads();
    #pragma unroll
    for (int ks = 0; ks < 2; ++ks){
      int kgl = ks*4 + lg;
      int Sg = (k0 >> 3) + kgl;
      s16x8 a = *(const s16x8*)&As[lrow*512 + ((Sg ^ (lrow & 7)) << 3)];
      int swzb = (kgl ^ (lrow & 7)) << 3;
      #pragma unroll
      for (int j = 0; j < 4; ++j){
        s16x8 b = *(const s16x8*)&Bs[(wn + j*16 + lrow)*64 + swzb];
        acc[j] = __builtin_amdgcn_mfma_f32_16x16x32_bf16(a, b, acc[j], 0, 0, 0);
      }
    }
    __syncthreads();
  }
  float bv[4], lwv[4], lbv[4];
  #pragma unroll
  for (int j=0;j<4;++j){
    int col = wn + j*16 + lrow;
    bv[j] = ob[col]; lwv[j] = lnw[col]; lbv[j] = lnb[col];
  }
  #pragma unroll
  for (int r=0;r<4;++r){
    float s=0.f, q=0.f;
    #pragma unroll
    for (int j=0;j<4;++j){ float v = acc[j][r] + bv[j]; s += v; q = fmaf(v,v,q); }
    #pragma unroll
    for (int m=1;m<=8;m<<=1){ s += __shfl_xor(s,m,64); q += __shfl_xor(q,m,64); }
    if (lrow == 0){ redS[wid][lg*4+r] = s; redQ[wid][lg*4+r] = q; }
  }
  __syncthreads();
  float* TT = (float*)Bs;   // MODE1 transpose buffer [256][17]
  #pragma unroll
  for (int r=0;r<4;++r){
    int row_l = lg*4 + r;
    int grow = bm + row_l;
    float S = redS[0][row_l]+redS[1][row_l]+redS[2][row_l]+redS[3][row_l];
    float Q = redQ[0][row_l]+redQ[1][row_l]+redQ[2][row_l]+redQ[3][row_l];
    float mu = S*(1.f/256.f);
    float var = Q*(1.f/256.f) - mu*mu;
    float inv = rsqrtf(var + 1e-5f);
    #pragma unroll
    for (int j=0;j<4;++j){
      int col = wn + j*16 + lrow;
      float v = acc[j][r] + bv[j];
      float o = resid[(size_t)grow*256 + col] + (v-mu)*inv*lwv[j] + lbv[j];
      if (MODE == 0){
        out[(size_t)grow*256 + 255 - col]  = o;
        outb[(size_t)grow*256 + 255 - col] = f2bf(o);
      } else {
        TT[col*17 + row_l] = o;
      }
    }
  }
  if (MODE == 1){
    __syncthreads();
    int c = tid;
    int b = bm >> 10, l0 = bm & 1023;
    float vv[16];
    #pragma unroll
    for (int i=0;i<16;++i) vv[i] = TT[c*17 + i];
    float* dst = out + ((size_t)(b*256) + (255 - c))*1024 + l0;
    #pragma unroll
    for (int i=0;i<4;++i)
      *(float4*)(dst + i*4) = make_float4(vv[i*4], vv[i*4+1], vv[i*4+2], vv[i*4+3]);
  }
}

extern "C" void kernel_launch(void* const* d_in, const int* in_sizes, int n_in,
                              void* d_out, int out_size, void* d_ws, size_t ws_size,
                              hipStream_t stream) {
  const float* x    = (const float*)d_in[0];
  const float* ln1w = (const float*)d_in[1];
  const float* ln1b = (const float*)d_in[2];
  const float* ln2w = (const float*)d_in[3];
  const float* ln2b = (const float*)d_in[4];

  const float* m1[11]; const float* m2[11];
  for (int i=0;i<11;++i){ m1[i] = (const float*)d_in[5+i]; m2[i] = (const float*)d_in[16+i]; }
  // order: in_w, in_b, conv_w, conv_b, xproj_w, dt_w, dt_b, A_log, D, out_w, out_b

  float* ws = (float*)d_ws;
  float* u0    = ws;                         // 524288
  u16*   u0b   = (u16*)(ws + 524288);        // 131072 fl
  float* xr    = ws + 655360;                // 2097152
  u16*   xscbl = (u16*)(ws + 2752512);       // 524288 fl : [2048][512]
  u16*   xscT  = (u16*)(ws + 3276800);       // 524288 fl : [512][2048]
  u16*   sresT = (u16*)(ws + 3801088);       // 524288 fl : [512][2048]
  u16*   dltT  = (u16*)(ws + 4325376);       // 524288 fl : [512][2048]
  u16*   BCb   = (u16*)(ws + 4849664);       // 32768 fl  : [2048][32]
  u16*   ygb   = (u16*)(ws + 4882432);       // 524288 fl : [2048][512]
  float* u2    = ws + 5406720;               // 524288
  u16*   u2b   = (u16*)(ws + 5931008);       // 131072 fl
  u16*   Wt1i  = (u16*)(ws + 6062080);       // 131072 fl
  u16*   Wt1x  = (u16*)(ws + 6193152);       // 147456 fl
  u16*   Wt1o  = (u16*)(ws + 6340608);       // 65536 fl
  u16*   Wt2i  = (u16*)(ws + 6406144);       // 131072 fl
  u16*   Wt2x  = (u16*)(ws + 6537216);       // 147456 fl
  u16*   Wt2o  = (u16*)(ws + 6684672);       // 65536 fl
  // total 6750208 floats = 27.0 MB

  dim3 b256(256);
  k_prep_trans<<<128 + 2*SEGP/256, b256, 0, stream>>>(x, u0, u0b,
      m1[0], m1[4], m1[5], m1[9], m2[0], m2[4], m2[5], m2[9],
      Wt1i, Wt1x, Wt1o, Wt2i, Wt2x, Wt2o);

  // ---- block 1
  k_gemm_mfma<<<dim3(16,32), b256, 0, stream>>>(u0b, Wt1i, m1[1], xr, NB*L, 2*DI, DM);
  k_conv_t<<<256, b256, 0, stream>>>(xr, m1[2], m1[3], xscT, xscbl, sresT);
  k_xproj<<<dim3(9,32), b256, 0, stream>>>(xscbl, Wt1x, m1[6], dltT, BCb);
  k_scan<<<256, b256, 0, stream>>>(dltT, xscT, BCb, sresT, m1[7], m1[8], ygb);
  k_out_ln<0><<<128, b256, 0, stream>>>(ygb, Wt1o, m1[10], u0, ln1w, ln1b, u2, u2b);

  // ---- block 2
  k_gemm_mfma<<<dim3(16,32), b256, 0, stream>>>(u2b, Wt2i, m2[1], xr, NB*L, 2*DI, DM);
  k_conv_t<<<256, b256, 0, stream>>>(xr, m2[2], m2[3], xscT, xscbl, sresT);
  k_xproj<<<dim3(9,32), b256, 0, stream>>>(xscbl, Wt2x, m2[6], dltT, BCb);
  k_scan<<<256, b256, 0, stream>>>(dltT, xscT, BCb, sresT, m2[7], m2[8], ygb);
  k_out_ln<1><<<128, b256, 0, stream>>>(ygb, Wt2o, m2[10], u2, ln2w, ln2b, (float*)d_out, nullptr);
}